// Round 7
// baseline (697.981 us; speedup 1.0000x reference)
//
#include <hip/hip_runtime.h>

// Problem constants (fixed by setup_inputs)
#define N_IMG 4
#define E_DIM 16
#define P_PIX 589824            // 768*768
#define C_CL 32

#define DELTA_VAR 0.5f
#define DELTA_DIST 2.0f
#define GAMMA_W 0.001f
#define EPS_F 1e-12f

// 576 blocks total (144/image), 3 blocks/CU capacity (LDS 42.6KB, VGPR<=168)
// -> all blocks co-resident (576 <= 768): spin grid-barrier is safe.
#define BPI 144
#define GRID_B (N_IMG * BPI)    // 576
#define PXB (P_PIX / BPI)       // 4096 px per block
#define NCH 4                   // chunks of 1024 px
#define TSTR 1036               // tile row stride in shorts (2072B = 6 banks offset/row)

// ws float offsets
#define WS_CTR 0                               // 16 ints (memset to 0 per launch)
#define WS_PART1 16                            // [GRID_B][544]
#define WS_SUMS (WS_PART1 + GRID_B * 544)      // [N][544]
#define WS_VARP (WS_SUMS + N_IMG * 544)        // [GRID_B]

typedef __attribute__((ext_vector_type(8))) short short8;
typedef __attribute__((ext_vector_type(16))) float float16v;

__device__ __forceinline__ short f2bf(float f) {
  return (short)(__float_as_uint(f) >> 16);  // trunc: unbiased for N(0,1) sums
}

// Device-scope grid barrier: release (wbL2) + arrive + spin acquire + inv.
__device__ __forceinline__ void grid_barrier(int* ctr, int expected) {
  __syncthreads();
  if (threadIdx.x == 0) {
    __threadfence();  // writeback dirty L2 (release to device coherence point)
    __hip_atomic_fetch_add(ctr, 1, __ATOMIC_ACQ_REL, __HIP_MEMORY_SCOPE_AGENT);
    while (__hip_atomic_load(ctr, __ATOMIC_ACQUIRE,
                             __HIP_MEMORY_SCOPE_AGENT) < expected)
      __builtin_amdgcn_s_sleep(8);
  }
  __syncthreads();
  __threadfence();  // acquire side: invalidate stale cached lines
}

__global__ __launch_bounds__(256, 3) void fused(const float* __restrict__ input,
                                                const int* __restrict__ target,
                                                float* __restrict__ ws,
                                                float* __restrict__ out) {
  __shared__ short s_tile[17 * TSTR];  // 35224 B: rows 0..15 data, 16 = ones
  __shared__ int s_lab[1024];          // 4096 B
  __shared__ float s_mean[C_CL * 17];  // phase B means (stride 17)
  __shared__ float s_invc[C_CL];
  __shared__ float s_redB[256];
  int* ctr = reinterpret_cast<int*>(ws) + WS_CTR;

  const int tid = threadIdx.x;
  const int wv = tid >> 6, l = tid & 63;
  const int bx = blockIdx.x, n = blockIdx.y;
  const int g = n * BPI + bx;
  const int* tgt = target + (size_t)n * P_PIX + bx * PXB;
  const float* inp = input + (size_t)n * E_DIM * P_PIX + bx * PXB;

  // ======================= Phase A: segment sums ==========================
  for (int i = tid; i < 1024; i += 256) s_tile[16 * TSTR + i] = (short)0x3F80;

  const int m = l & 31, half = l >> 5;
  const int brow = (m < 17) ? m : 16;  // cols 17..31 unused, clamp (no OOB)
  const short ONE = 0x3F80;
  float16v acc;
#pragma unroll
  for (int i = 0; i < 16; ++i) acc[i] = 0.f;

  for (int c = 0; c < NCH; ++c) {
    const int p = c * 1024 + tid * 4;
    const int4 lab = *reinterpret_cast<const int4*>(tgt + p);
    float4 v[E_DIM];
#pragma unroll
    for (int e = 0; e < E_DIM; ++e)
      v[e] = *reinterpret_cast<const float4*>(inp + (size_t)e * P_PIX + p);
    __syncthreads();  // previous chunk's MFMA reads complete
    *reinterpret_cast<int4*>(&s_lab[tid * 4]) = lab;
#pragma unroll
    for (int e = 0; e < E_DIM; ++e) {
      short4 b4;
      b4.x = f2bf(v[e].x); b4.y = f2bf(v[e].y);
      b4.z = f2bf(v[e].z); b4.w = f2bf(v[e].w);
      *reinterpret_cast<short4*>(&s_tile[e * TSTR + tid * 4]) = b4;
    }
    __syncthreads();
    const int k0w = wv * 256;
#pragma unroll
    for (int s = 0; s < 16; ++s) {
      const int k0 = k0w + s * 16 + half * 8;
      const int4 la = *reinterpret_cast<const int4*>(&s_lab[k0]);
      const int4 lb = *reinterpret_cast<const int4*>(&s_lab[k0 + 4]);
      const short4 b0 = *reinterpret_cast<const short4*>(&s_tile[brow * TSTR + k0]);
      const short4 b1 = *reinterpret_cast<const short4*>(&s_tile[brow * TSTR + k0 + 4]);
      short8 a, b;
      a[0] = (la.x == m) ? ONE : 0;
      a[1] = (la.y == m) ? ONE : 0;
      a[2] = (la.z == m) ? ONE : 0;
      a[3] = (la.w == m) ? ONE : 0;
      a[4] = (lb.x == m) ? ONE : 0;
      a[5] = (lb.y == m) ? ONE : 0;
      a[6] = (lb.z == m) ? ONE : 0;
      a[7] = (lb.w == m) ? ONE : 0;
      b[0] = b0.x; b[1] = b0.y; b[2] = b0.z; b[3] = b0.w;
      b[4] = b1.x; b[5] = b1.y; b[6] = b1.z; b[7] = b1.w;
      acc = __builtin_amdgcn_mfma_f32_32x32x16_bf16(a, b, acc, 0, 0, 0);
    }
  }

  // Cross-wave reduce (alias tile as float scratch), plain partial store.
  __syncthreads();
  float* s_red = reinterpret_cast<float*>(s_tile);
#pragma unroll
  for (int r = 0; r < 16; ++r) s_red[wv * 1024 + r * 64 + l] = acc[r];
  __syncthreads();
  // C/D layout (verified): col = lane&31, row = (reg&3) + 8*(reg>>2) + 4*(lane>>5)
  float* part = ws + WS_PART1 + (size_t)g * 544;
  for (int i = tid; i < C_CL * 17; i += 256) {
    const int row = i / 17, col = i - row * 17;
    const int lane = col | (((row >> 2) & 1) << 5);
    const int reg = (row & 3) | ((row >> 3) << 2);
    const int idx = reg * 64 + lane;
    part[i] = s_red[idx] + s_red[1024 + idx] + s_red[2048 + idx] +
              s_red[3072 + idx];
  }

  grid_barrier(&ctr[0], GRID_B);

  // ================== Reduce partials (one block per image) ===============
  if (bx == 0) {
    const float* pbase = ws + WS_PART1 + (size_t)n * BPI * 544;
    float* sums = ws + WS_SUMS + n * 544;
    for (int i = tid; i < 544; i += 256) {
      float a2 = 0.f;
#pragma unroll 8
      for (int b = 0; b < BPI; ++b) a2 += pbase[(size_t)b * 544 + i];
      sums[i] = a2;
    }
  }

  grid_barrier(&ctr[1], GRID_B);

  // ======================= Phase B: variance term =========================
  const float* sums = ws + WS_SUMS + n * 544;
  for (int i = tid; i < C_CL * E_DIM; i += 256) {
    const int c2 = i >> 4, e = i & 15;
    s_mean[c2 * 17 + e] = sums[c2 * 17 + e] / sums[c2 * 17 + 16];
  }
  if (tid < C_CL) s_invc[tid] = 1.0f / sums[tid * 17 + 16];
  __syncthreads();

  float vacc = 0.f;
  for (int c = 0; c < NCH; ++c) {
    const int p = c * 1024 + tid * 4;
    const int4 lab = *reinterpret_cast<const int4*>(tgt + p);
    float4 v[E_DIM];
#pragma unroll
    for (int e = 0; e < E_DIM; ++e)
      v[e] = *reinterpret_cast<const float4*>(inp + (size_t)e * P_PIX + p);
    const float* mx = s_mean + lab.x * 17;
    const float* my = s_mean + lab.y * 17;
    const float* mz = s_mean + lab.z * 17;
    const float* mw = s_mean + lab.w * 17;
    float ax = 0.f, ay = 0.f, az = 0.f, aw = 0.f;
#pragma unroll
    for (int e = 0; e < E_DIM; ++e) {
      const float dx = v[e].x - mx[e];
      const float dy = v[e].y - my[e];
      const float dz = v[e].z - mz[e];
      const float dw = v[e].w - mw[e];
      ax += dx * dx; ay += dy * dy; az += dz * dz; aw += dw * dw;
    }
    float d, h;
    d = sqrtf(fmaxf(ax, EPS_F)); h = fmaxf(d - DELTA_VAR, 0.f);
    vacc += h * h * s_invc[lab.x];
    d = sqrtf(fmaxf(ay, EPS_F)); h = fmaxf(d - DELTA_VAR, 0.f);
    vacc += h * h * s_invc[lab.y];
    d = sqrtf(fmaxf(az, EPS_F)); h = fmaxf(d - DELTA_VAR, 0.f);
    vacc += h * h * s_invc[lab.z];
    d = sqrtf(fmaxf(aw, EPS_F)); h = fmaxf(d - DELTA_VAR, 0.f);
    vacc += h * h * s_invc[lab.w];
  }
  s_redB[tid] = vacc;
  __syncthreads();
  for (int s2 = 128; s2 > 0; s2 >>= 1) {
    if (tid < s2) s_redB[tid] += s_redB[tid + s2];
    __syncthreads();
  }
  if (tid == 0) ws[WS_VARP + g] = s_redB[0];

  // =================== Final: arrive-only; block 0 finalizes ==============
  __syncthreads();
  if (tid == 0) {
    __threadfence();
    __hip_atomic_fetch_add(&ctr[2], 1, __ATOMIC_ACQ_REL,
                           __HIP_MEMORY_SCOPE_AGENT);
  }
  if (g != 0) return;
  if (tid == 0) {
    while (__hip_atomic_load(&ctr[2], __ATOMIC_ACQUIRE,
                             __HIP_MEMORY_SCOPE_AGENT) < GRID_B)
      __builtin_amdgcn_s_sleep(8);
  }
  __syncthreads();
  __threadfence();

  float* s_meanF = reinterpret_cast<float*>(s_tile);  // 2048 floats
  for (int i = tid; i < N_IMG * C_CL * E_DIM; i += 256) {
    const int nn = i >> 9, rem = i & 511;
    const int c2 = rem >> 4, e = rem & 15;
    s_meanF[i] = ws[WS_SUMS + nn * 544 + c2 * 17 + e] /
                 ws[WS_SUMS + nn * 544 + c2 * 17 + 16];
  }
  __syncthreads();

  float acc2 = 0.f;
  for (int i = tid; i < GRID_B; i += 256)
    acc2 += ws[WS_VARP + i] * (1.0f / C_CL);
  for (int i = tid; i < N_IMG * C_CL; i += 256) {
    float nrm2 = 0.f;
    const float* mm = s_meanF + i * E_DIM;
#pragma unroll
    for (int e = 0; e < E_DIM; ++e) nrm2 += mm[e] * mm[e];
    acc2 += GAMMA_W * sqrtf(fmaxf(nrm2, EPS_F)) * (1.0f / C_CL);
  }
  for (int t = tid; t < N_IMG * C_CL * C_CL; t += 256) {
    const int nn = t / (C_CL * C_CL);
    const int r = t - nn * C_CL * C_CL;
    const int a2 = r >> 5, b2 = r & 31;
    if (a2 != b2) {
      const float* ma = s_meanF + (nn * C_CL + a2) * E_DIM;
      const float* mb = s_meanF + (nn * C_CL + b2) * E_DIM;
      float d2 = 0.f;
#pragma unroll
      for (int e = 0; e < E_DIM; ++e) {
        const float df = ma[e] - mb[e];
        d2 += df * df;
      }
      const float dist = sqrtf(fmaxf(d2, EPS_F));
      const float hd = fmaxf(2.f * DELTA_DIST - dist, 0.f);
      acc2 += hd * hd * (1.0f / (C_CL * (C_CL - 1)));
    }
  }
  s_redB[tid] = acc2;
  __syncthreads();
  for (int s2 = 128; s2 > 0; s2 >>= 1) {
    if (tid < s2) s_redB[tid] += s_redB[tid + s2];
    __syncthreads();
  }
  if (tid == 0) out[0] = s_redB[0] * (1.0f / N_IMG);
}

extern "C" void kernel_launch(void* const* d_in, const int* in_sizes, int n_in,
                              void* d_out, int out_size, void* d_ws,
                              size_t ws_size, hipStream_t stream) {
  const float* input = (const float*)d_in[0];
  const int* target = (const int*)d_in[1];
  float* ws = (float*)d_ws;
  float* out = (float*)d_out;

  hipMemsetAsync(ws, 0, 64, stream);  // zero barrier counters only
  fused<<<dim3(BPI, N_IMG), 256, 0, stream>>>(input, target, ws, out);
}